// Round 1
// baseline (655.539 us; speedup 1.0000x reference)
//
#include <hip/hip_runtime.h>
#include <hip/hip_bf16.h>

#define N_NODES 50000
#define N_EDGES 600000
#define D_IN    128
#define D_HID   1024
#define D_OUT   128

// ---------------------------------------------------------------------------
// Workspace layout (bytes):
//   (hbf slot retained but unused after gather+MLP fusion)
//   eid    : [N_EDGES] int        @ 12,800,000   ( 2,400,000)
//   off    : [N_NODES+1] int      @ 15,200,000   (   200,016)
//   cursor : [N_NODES] int        @ 15,400,016   (   200,000)
//   deg    : [N_NODES] int        @ 15,600,016   (   200,000)
//   bsum   : [256] int            @ 15,800,016   (     1,024)
//   W1T    : [1024*128] bf16      @ 15,801,040   (   262,144)   [n][k]
//   W2T    : [128*1024] bf16      @ 16,063,184   (   262,144)   [n][k]
// ---------------------------------------------------------------------------
#define WS_EID    12800000
#define WS_OFF    15200000
#define WS_CURSOR 15400016
#define WS_DEG    15600016
#define WS_BSUM   15800016
#define WS_W1T    15801040
#define WS_W2T    16063184

typedef short bf16x8 __attribute__((ext_vector_type(8)));
typedef float f32x4  __attribute__((ext_vector_type(4)));

// ---------------------------------------------------------------------------
// CSR step 1: histogram of dst
// ---------------------------------------------------------------------------
__global__ __launch_bounds__(256) void hist_kernel(
    const int* __restrict__ dst, int* __restrict__ deg)
{
    int e = blockIdx.x * blockDim.x + threadIdx.x;
    if (e < N_EDGES) atomicAdd(&deg[dst[e]], 1);
}

// ---------------------------------------------------------------------------
// CSR step 2a: per-block sums of deg (coalesced). 196 blocks x 256.
// ---------------------------------------------------------------------------
__global__ __launch_bounds__(256) void scan1_kernel(
    const int* __restrict__ deg, int* __restrict__ bsum)
{
    __shared__ int red[256];
    int t = threadIdx.x;
    int idx = blockIdx.x * 256 + t;
    red[t] = (idx < N_NODES) ? deg[idx] : 0;
    __syncthreads();
    for (int s = 128; s > 0; s >>= 1) {
        if (t < s) red[t] += red[t + s];
        __syncthreads();
    }
    if (t == 0) bsum[blockIdx.x] = red[0];
}

// ---------------------------------------------------------------------------
// CSR step 2b: exclusive scan of 196 block sums (single small block).
// Also writes off[N_NODES] = total.
// ---------------------------------------------------------------------------
#define SCAN_NB 196
__global__ __launch_bounds__(256) void scan2_kernel(
    int* __restrict__ bsum, int* __restrict__ off)
{
    __shared__ int sh[256];
    int t = threadIdx.x;
    int v = (t < SCAN_NB) ? bsum[t] : 0;
    sh[t] = v;
    __syncthreads();
    for (int ofs = 1; ofs < 256; ofs <<= 1) {
        int u = (t >= ofs) ? sh[t - ofs] : 0;
        __syncthreads();
        sh[t] += u;
        __syncthreads();
    }
    if (t < SCAN_NB) bsum[t] = sh[t] - v;       // exclusive
    if (t == 255) off[N_NODES] = sh[255];       // total == N_EDGES
}

// ---------------------------------------------------------------------------
// CSR step 2c: block-local scan + block offset -> off[], cursor[]
// ---------------------------------------------------------------------------
__global__ __launch_bounds__(256) void scan3_kernel(
    const int* __restrict__ deg, const int* __restrict__ bsum,
    int* __restrict__ off, int* __restrict__ cursor)
{
    __shared__ int sh[256];
    int t = threadIdx.x;
    int idx = blockIdx.x * 256 + t;
    int v = (idx < N_NODES) ? deg[idx] : 0;
    sh[t] = v;
    __syncthreads();
    for (int ofs = 1; ofs < 256; ofs <<= 1) {
        int u = (t >= ofs) ? sh[t - ofs] : 0;
        __syncthreads();
        sh[t] += u;
        __syncthreads();
    }
    if (idx < N_NODES) {
        int ex = bsum[blockIdx.x] + sh[t] - v;
        off[idx] = ex;
        cursor[idx] = ex;
    }
}

// ---------------------------------------------------------------------------
// CSR step 3: drop edge ids into dst buckets
// ---------------------------------------------------------------------------
__global__ __launch_bounds__(256) void fill_kernel(
    const int* __restrict__ dst, int* __restrict__ cursor, int* __restrict__ eid)
{
    int e = blockIdx.x * blockDim.x + threadIdx.x;
    if (e < N_EDGES) {
        int pos = atomicAdd(&cursor[dst[e]], 1);
        eid[pos] = e;
    }
}

// ---------------------------------------------------------------------------
// Merged transpose + fp32->bf16 convert for BOTH weight matrices in one
// launch. Blocks [0,128): W1[128][1024] -> W1T[1024][128].
// Blocks [128,256): W2[1024][128] -> W2T[128][1024]. Dims divisible by 32,
// so no bounds checks.
// ---------------------------------------------------------------------------
__global__ __launch_bounds__(256) void transpose_cvt2_kernel(
    const float* __restrict__ W1, __hip_bfloat16* __restrict__ w1t,
    const float* __restrict__ W2, __hip_bfloat16* __restrict__ w2t)
{
    __shared__ float tile[32][33];
    int b = blockIdx.x;
    const float* in;
    __hip_bfloat16* outp;
    int rows, cols, c0, r0;
    if (b < 128) {
        in = W1; outp = w1t; rows = D_IN; cols = D_HID;
        c0 = (b & 31) * 32; r0 = (b >> 5) * 32;          // grid (32,4)
    } else {
        int bb = b - 128;
        in = W2; outp = w2t; rows = D_HID; cols = D_OUT;
        c0 = (bb & 3) * 32; r0 = (bb >> 2) * 32;         // grid (4,32)
    }
    int tx = threadIdx.x & 31, ty = threadIdx.x >> 5;    // ty 0..7
    #pragma unroll
    for (int i = 0; i < 32; i += 8)
        tile[ty + i][tx] = in[(size_t)(r0 + ty + i) * cols + (c0 + tx)];
    __syncthreads();
    #pragma unroll
    for (int i = 0; i < 32; i += 8)
        outp[(size_t)(c0 + ty + i) * rows + (r0 + tx)] =
            __float2bfloat16(tile[tx][ty + i]);
}

// ---------------------------------------------------------------------------
// FUSED gather + MFMA MLP. 64 nodes/block, 4 waves.
//
// Phase 1 (gather): wave wv owns tile rows wv*16..wv*16+15. For each node,
//   wave-scalar eid/src indices (readfirstlane), lane holds float2 cols
//   (2l, 2l+1); 4-edge unroll -> 4 independent 1KB load chains. Result is
//   written straight into h_s (bf16, A-operand layout) -- no global round
//   trip. Blocks at different phases overlap HBM-bound gather with
//   MFMA-bound MLP across the CU.
//
// Phase 2 (MLP):
//   Layer1: wave w computes hid[:, jb + w*16 .. +16); A (h tile) in regs,
//           B streamed from W1T[n][k] (contiguous 16B frags).
//   Hidden chunk relu'd -> bf16 -> q_s[parity] (A-operand layout).
//   q_s is DOUBLE-BUFFERED: single __syncthreads() per chunk (write->sync->
//   read); chunk k+2's write to the same buffer is separated from chunk k's
//   reads by the chunk-k+1 barrier.
//   Layer2: wave w computes out[:, w*32 .. +32), K = chunk, B from W2T[n][k].
// ---------------------------------------------------------------------------
#define HS_STRIDE 136   // shorts per h_s row (272 B = 17*16, banks shift 4/row)
#define QS_STRIDE 72    // shorts per q_s row (144 B =  9*16)

__global__ __launch_bounds__(256) void fused_gnn_kernel(
    const float* __restrict__ feat,
    const float* __restrict__ edge_feat,
    const int*   __restrict__ src,
    const int*   __restrict__ eid,
    const int*   __restrict__ off,
    const __hip_bfloat16* __restrict__ w1t,   // [1024][128]
    const float* __restrict__ b1,             // [1024]
    const __hip_bfloat16* __restrict__ w2t,   // [128][1024]
    const float* __restrict__ b2,             // [128]
    float* __restrict__ out)                  // [N][128]
{
    __shared__ __align__(16) short h_s[64 * HS_STRIDE];      // 17.4 KB
    __shared__ __align__(16) short q_s[2][64 * QS_STRIDE];   // 18.4 KB

    const int t    = threadIdx.x;
    const int wv   = t >> 6;
    const int lane = t & 63;
    const int half = lane >> 4;    // quad 0..3
    const int lid  = lane & 15;
    const int nb   = blockIdx.x * 64;

    const short* w1s = (const short*)w1t;
    const short* w2s = (const short*)w2t;

    // ---- phase 1: gather straight into h_s ----
    for (int j = 0; j < 16; ++j) {
        const int r = wv * 16 + j;
        const int n = nb + r;
        float2 a0 = make_float2(0.f, 0.f), a1 = a0, a2 = a0, a3 = a0;
        if (n < N_NODES) {
            int i   = __builtin_amdgcn_readfirstlane(off[n]);
            int end = __builtin_amdgcn_readfirstlane(off[n + 1]);
            for (; i + 3 < end; i += 4) {
                int e0 = __builtin_amdgcn_readfirstlane(eid[i]);
                int e1 = __builtin_amdgcn_readfirstlane(eid[i + 1]);
                int e2 = __builtin_amdgcn_readfirstlane(eid[i + 2]);
                int e3 = __builtin_amdgcn_readfirstlane(eid[i + 3]);
                int s0 = __builtin_amdgcn_readfirstlane(src[e0]);
                int s1 = __builtin_amdgcn_readfirstlane(src[e1]);
                int s2 = __builtin_amdgcn_readfirstlane(src[e2]);
                int s3 = __builtin_amdgcn_readfirstlane(src[e3]);
                float2 f0 = ((const float2*)(edge_feat + (size_t)e0 * D_IN))[lane];
                float2 g0 = ((const float2*)(feat      + (size_t)s0 * D_IN))[lane];
                float2 f1 = ((const float2*)(edge_feat + (size_t)e1 * D_IN))[lane];
                float2 g1 = ((const float2*)(feat      + (size_t)s1 * D_IN))[lane];
                float2 f2 = ((const float2*)(edge_feat + (size_t)e2 * D_IN))[lane];
                float2 g2 = ((const float2*)(feat      + (size_t)s2 * D_IN))[lane];
                float2 f3 = ((const float2*)(edge_feat + (size_t)e3 * D_IN))[lane];
                float2 g3 = ((const float2*)(feat      + (size_t)s3 * D_IN))[lane];
                a0.x += f0.x + g0.x;  a0.y += f0.y + g0.y;
                a1.x += f1.x + g1.x;  a1.y += f1.y + g1.y;
                a2.x += f2.x + g2.x;  a2.y += f2.y + g2.y;
                a3.x += f3.x + g3.x;  a3.y += f3.y + g3.y;
            }
            for (; i < end; ++i) {
                int e = __builtin_amdgcn_readfirstlane(eid[i]);
                int s = __builtin_amdgcn_readfirstlane(src[e]);
                float2 f = ((const float2*)(edge_feat + (size_t)e * D_IN))[lane];
                float2 g = ((const float2*)(feat      + (size_t)s * D_IN))[lane];
                a0.x += f.x + g.x;  a0.y += f.y + g.y;
            }
        }
        float sx = (a0.x + a1.x) + (a2.x + a3.x);
        float sy = (a0.y + a1.y) + (a2.y + a3.y);
        __hip_bfloat162 hv;
        hv.x = __float2bfloat16(sx);
        hv.y = __float2bfloat16(sy);
        *(__hip_bfloat162*)&h_s[r * HS_STRIDE + lane * 2] = hv;
    }
    __syncthreads();

    // ---- A fragments for layer 1 (held in registers for all chunks) ----
    bf16x8 afrag[4][4];
    #pragma unroll
    for (int mt = 0; mt < 4; ++mt)
        #pragma unroll
        for (int ks = 0; ks < 4; ++ks)
            afrag[mt][ks] = *(const bf16x8*)&h_s[(mt * 16 + lid) * HS_STRIDE + ks * 32 + half * 8];

    f32x4 acc[4][2];
    #pragma unroll
    for (int mt = 0; mt < 4; ++mt) {
        acc[mt][0] = f32x4{0.f, 0.f, 0.f, 0.f};
        acc[mt][1] = f32x4{0.f, 0.f, 0.f, 0.f};
    }

    const int ncol1 = wv * 16 + lid;   // within-chunk hidden column for layer-1 B

    int pb = 0;
    for (int jb = 0; jb < D_HID; jb += 64, pb ^= 1) {
        // ---- layer 1 ----
        float bias = b1[jb + ncol1];
        bf16x8 bfrag[4];
        #pragma unroll
        for (int ks = 0; ks < 4; ++ks)
            bfrag[ks] = *(const bf16x8*)&w1s[(size_t)(jb + ncol1) * 128 + ks * 32 + half * 8];

        f32x4 c1[4];
        #pragma unroll
        for (int mt = 0; mt < 4; ++mt) {
            f32x4 c = f32x4{bias, bias, bias, bias};
            #pragma unroll
            for (int ks = 0; ks < 4; ++ks)
                c = __builtin_amdgcn_mfma_f32_16x16x32_bf16(afrag[mt][ks], bfrag[ks], c, 0, 0, 0);
            c1[mt] = c;
        }

        // write this chunk into q_s[pb]; chunk k-1's reads of q_s[pb^1] are
        // already separated from the NEXT write to pb^1 by this barrier.
        #pragma unroll
        for (int mt = 0; mt < 4; ++mt) {
            #pragma unroll
            for (int r = 0; r < 4; ++r) {
                float v = fmaxf(c1[mt][r], 0.f);
                __hip_bfloat16 bv = __float2bfloat16(v);
                q_s[pb][(mt * 16 + half * 4 + r) * QS_STRIDE + wv * 16 + lid] = *(short*)&bv;
            }
        }
        __syncthreads();

        // ---- layer 2 ----
        bf16x8 a2f[4][2];
        #pragma unroll
        for (int mt = 0; mt < 4; ++mt)
            #pragma unroll
            for (int ks = 0; ks < 2; ++ks)
                a2f[mt][ks] = *(const bf16x8*)&q_s[pb][(mt * 16 + lid) * QS_STRIDE + ks * 32 + half * 8];

        #pragma unroll
        for (int nt = 0; nt < 2; ++nt) {
            #pragma unroll
            for (int ks = 0; ks < 2; ++ks) {
                bf16x8 b2f = *(const bf16x8*)&w2s[(size_t)(wv * 32 + nt * 16 + lid) * 1024 + jb + ks * 32 + half * 8];
                #pragma unroll
                for (int mt = 0; mt < 4; ++mt)
                    acc[mt][nt] = __builtin_amdgcn_mfma_f32_16x16x32_bf16(a2f[mt][ks], b2f, acc[mt][nt], 0, 0, 0);
            }
        }
    }

    // ---- epilogue ----
    #pragma unroll
    for (int nt = 0; nt < 2; ++nt) {
        int col = wv * 32 + nt * 16 + lid;
        float bv = b2[col];
        #pragma unroll
        for (int mt = 0; mt < 4; ++mt) {
            #pragma unroll
            for (int r = 0; r < 4; ++r) {
                int row = nb + mt * 16 + half * 4 + r;
                if (row < N_NODES)
                    out[(size_t)row * D_OUT + col] = acc[mt][nt][r] + bv;
            }
        }
    }
}

// ---------------------------------------------------------------------------
extern "C" void kernel_launch(void* const* d_in, const int* in_sizes, int n_in,
                              void* d_out, int out_size, void* d_ws, size_t ws_size,
                              hipStream_t stream) {
    const float* feat      = (const float*)d_in[0];
    const float* edge_feat = (const float*)d_in[1];
    const int*   src       = (const int*)d_in[2];
    const int*   dst       = (const int*)d_in[3];
    const float* W1        = (const float*)d_in[4];
    const float* b1        = (const float*)d_in[5];
    const float* W2        = (const float*)d_in[6];
    const float* b2        = (const float*)d_in[7];
    float* out = (float*)d_out;

    char* ws = (char*)d_ws;
    int*   eid    = (int*)(ws + WS_EID);
    int*   off    = (int*)(ws + WS_OFF);
    int*   cursor = (int*)(ws + WS_CURSOR);
    int*   deg    = (int*)(ws + WS_DEG);
    int*   bsum   = (int*)(ws + WS_BSUM);
    __hip_bfloat16* w1t = (__hip_bfloat16*)(ws + WS_W1T);
    __hip_bfloat16* w2t = (__hip_bfloat16*)(ws + WS_W2T);

    hipMemsetAsync(deg, 0, (size_t)N_NODES * sizeof(int), stream);

    // CSR build
    hist_kernel<<<(N_EDGES + 255) / 256, 256, 0, stream>>>(dst, deg);
    scan1_kernel<<<SCAN_NB, 256, 0, stream>>>(deg, bsum);
    scan2_kernel<<<1, 256, 0, stream>>>(bsum, off);
    scan3_kernel<<<SCAN_NB, 256, 0, stream>>>(deg, bsum, off, cursor);
    fill_kernel<<<(N_EDGES + 255) / 256, 256, 0, stream>>>(dst, cursor, eid);

    // both weight transposes in one launch
    transpose_cvt2_kernel<<<256, 256, 0, stream>>>(W1, w1t, W2, w2t);

    // fused gather + MFMA MLP
    fused_gnn_kernel<<<(N_NODES + 63) / 64, 256, 0, stream>>>(
        feat, edge_feat, src, eid, off, w1t, b1, w2t, b2, out);
}

// Round 2
// 636.130 us; speedup vs baseline: 1.0305x; 1.0305x over previous
//
#include <hip/hip_runtime.h>
#include <hip/hip_bf16.h>

#define N_NODES 50000
#define N_EDGES 600000
#define D_IN    128
#define D_HID   1024
#define D_OUT   128

// ---------------------------------------------------------------------------
// Workspace layout (bytes):
//   pairs  : [N_EDGES] int2       @ 0            ( 4,800,000)  {eid, src}
//   off    : [N_NODES+1] int      @  4,800,000   (   200,016)
//   cursor : [N_NODES] int        @  5,000,016   (   200,000)
//   deg    : [N_NODES] int        @  5,200,016   (   200,000)
//   bsum   : [256] int            @  5,400,016   (     1,024)
//   W1T    : [1024*128] bf16      @  5,401,040   (   262,144)   [n][k]
//   W2T    : [128*1024] bf16      @  5,663,184   (   262,144)   [n][k]
// ---------------------------------------------------------------------------
#define WS_PAIRS  0
#define WS_OFF    4800000
#define WS_CURSOR 5000016
#define WS_DEG    5200016
#define WS_BSUM   5400016
#define WS_W1T    5401040
#define WS_W2T    5663184

typedef short bf16x8 __attribute__((ext_vector_type(8)));
typedef short s16x4  __attribute__((ext_vector_type(4)));
typedef float f32x4  __attribute__((ext_vector_type(4)));
typedef int   i32x2  __attribute__((ext_vector_type(2)));

// ---------------------------------------------------------------------------
// CSR step 1: histogram of dst
// ---------------------------------------------------------------------------
__global__ __launch_bounds__(256) void hist_kernel(
    const int* __restrict__ dst, int* __restrict__ deg)
{
    int e = blockIdx.x * blockDim.x + threadIdx.x;
    if (e < N_EDGES) atomicAdd(&deg[dst[e]], 1);
}

// ---------------------------------------------------------------------------
// CSR step 2a: per-block sums of deg (coalesced). 196 blocks x 256.
// ---------------------------------------------------------------------------
__global__ __launch_bounds__(256) void scan1_kernel(
    const int* __restrict__ deg, int* __restrict__ bsum)
{
    __shared__ int red[256];
    int t = threadIdx.x;
    int idx = blockIdx.x * 256 + t;
    red[t] = (idx < N_NODES) ? deg[idx] : 0;
    __syncthreads();
    for (int s = 128; s > 0; s >>= 1) {
        if (t < s) red[t] += red[t + s];
        __syncthreads();
    }
    if (t == 0) bsum[blockIdx.x] = red[0];
}

// ---------------------------------------------------------------------------
// CSR step 2b: exclusive scan of 196 block sums (single small block).
// Also writes off[N_NODES] = total.
// ---------------------------------------------------------------------------
#define SCAN_NB 196
__global__ __launch_bounds__(256) void scan2_kernel(
    int* __restrict__ bsum, int* __restrict__ off)
{
    __shared__ int sh[256];
    int t = threadIdx.x;
    int v = (t < SCAN_NB) ? bsum[t] : 0;
    sh[t] = v;
    __syncthreads();
    for (int ofs = 1; ofs < 256; ofs <<= 1) {
        int u = (t >= ofs) ? sh[t - ofs] : 0;
        __syncthreads();
        sh[t] += u;
        __syncthreads();
    }
    if (t < SCAN_NB) bsum[t] = sh[t] - v;       // exclusive
    if (t == 255) off[N_NODES] = sh[255];       // total == N_EDGES
}

// ---------------------------------------------------------------------------
// CSR step 2c: block-local scan + block offset -> off[], cursor[]
// ---------------------------------------------------------------------------
__global__ __launch_bounds__(256) void scan3_kernel(
    const int* __restrict__ deg, const int* __restrict__ bsum,
    int* __restrict__ off, int* __restrict__ cursor)
{
    __shared__ int sh[256];
    int t = threadIdx.x;
    int idx = blockIdx.x * 256 + t;
    int v = (idx < N_NODES) ? deg[idx] : 0;
    sh[t] = v;
    __syncthreads();
    for (int ofs = 1; ofs < 256; ofs <<= 1) {
        int u = (t >= ofs) ? sh[t - ofs] : 0;
        __syncthreads();
        sh[t] += u;
        __syncthreads();
    }
    if (idx < N_NODES) {
        int ex = bsum[blockIdx.x] + sh[t] - v;
        off[idx] = ex;
        cursor[idx] = ex;
    }
}

// ---------------------------------------------------------------------------
// CSR step 3: drop {eid, src} pairs into dst buckets. Packing src here
// removes one dependent load level from the gather's pointer chain.
// ---------------------------------------------------------------------------
__global__ __launch_bounds__(256) void fill_kernel(
    const int* __restrict__ dst, const int* __restrict__ src,
    int* __restrict__ cursor, int* __restrict__ pairs)
{
    int e = blockIdx.x * blockDim.x + threadIdx.x;
    if (e < N_EDGES) {
        int s = src[e];                       // coalesced
        int pos = atomicAdd(&cursor[dst[e]], 1);
        i32x2 v; v.x = e; v.y = s;
        *(i32x2*)(pairs + 2 * (size_t)pos) = v;   // 8B scatter
    }
}

// ---------------------------------------------------------------------------
// Merged transpose + fp32->bf16 convert for BOTH weight matrices in one
// launch. Blocks [0,128): W1[128][1024] -> W1T[1024][128].
// Blocks [128,256): W2[1024][128] -> W2T[128][1024].
// ---------------------------------------------------------------------------
__global__ __launch_bounds__(256) void transpose_cvt2_kernel(
    const float* __restrict__ W1, __hip_bfloat16* __restrict__ w1t,
    const float* __restrict__ W2, __hip_bfloat16* __restrict__ w2t)
{
    __shared__ float tile[32][33];
    int b = blockIdx.x;
    const float* in;
    __hip_bfloat16* outp;
    int rows, cols, c0, r0;
    if (b < 128) {
        in = W1; outp = w1t; rows = D_IN; cols = D_HID;
        c0 = (b & 31) * 32; r0 = (b >> 5) * 32;          // grid (32,4)
    } else {
        int bb = b - 128;
        in = W2; outp = w2t; rows = D_HID; cols = D_OUT;
        c0 = (bb & 3) * 32; r0 = (bb >> 2) * 32;         // grid (4,32)
    }
    int tx = threadIdx.x & 31, ty = threadIdx.x >> 5;    // ty 0..7
    #pragma unroll
    for (int i = 0; i < 32; i += 8)
        tile[ty + i][tx] = in[(size_t)(r0 + ty + i) * cols + (c0 + tx)];
    __syncthreads();
    #pragma unroll
    for (int i = 0; i < 32; i += 8)
        outp[(size_t)(c0 + ty + i) * rows + (r0 + tx)] =
            __float2bfloat16(tile[tx][ty + i]);
}

// ---------------------------------------------------------------------------
// FUSED gather + MFMA MLP. 64 nodes/block, 4 waves.
//
// Phase 1 (gather, latency-optimized): wave wv owns rows wv*16..+15.
//   - off[] for all 17 boundaries preloaded via one vector load + __shfl.
//   - Per-lane indexing: half-wave eh=lane>>5 handles edge (i+2k+eh), lane
//     ln=lane&31 holds float4 cols ln*4..+3 (16B/lane, 512B/edge coalesced).
//   - {eid,src} come from one streaming i32x2 pair load -> feature gathers
//     are ONE dependent level deep; 8 edges (16 x 512B) in flight.
//   - Cross-half __shfl_xor(32) reduce; half-wave 0 writes bf16x4 to h_s.
//
// Phase 2 (MLP): unchanged from round 1 (double-buffered q_s, 1 barrier per
//   64-col hidden chunk).
// ---------------------------------------------------------------------------
#define HS_STRIDE 136   // shorts per h_s row (272 B = 17*16, banks shift 4/row)
#define QS_STRIDE 72    // shorts per q_s row (144 B =  9*16)

__global__ __launch_bounds__(256) void fused_gnn_kernel(
    const float* __restrict__ feat,
    const float* __restrict__ edge_feat,
    const int*   __restrict__ pairs,          // [E] {eid, src}
    const int*   __restrict__ off,
    const __hip_bfloat16* __restrict__ w1t,   // [1024][128]
    const float* __restrict__ b1,             // [1024]
    const __hip_bfloat16* __restrict__ w2t,   // [128][1024]
    const float* __restrict__ b2,             // [128]
    float* __restrict__ out)                  // [N][128]
{
    __shared__ __align__(16) short h_s[64 * HS_STRIDE];      // 17.4 KB
    __shared__ __align__(16) short q_s[2][64 * QS_STRIDE];   // 18.4 KB

    const int t    = threadIdx.x;
    const int wv   = t >> 6;
    const int lane = t & 63;
    const int half = lane >> 4;    // quad 0..3 (MFMA layout)
    const int lid  = lane & 15;
    const int nb   = blockIdx.x * 64;

    const short* w1s = (const short*)w1t;
    const short* w2s = (const short*)w2t;

    // ---- phase 1: gather straight into h_s ----
    const int eh = lane >> 5;      // which edge of a pair this half-wave does
    const int ln = lane & 31;      // float4 column group

    // preload off[] boundaries for this wave's 16 rows (lanes 0..16)
    int my_off = 0;
    {
        int oidx = nb + wv * 16 + lane;
        if (lane <= 16) {
            int c = oidx > N_NODES ? N_NODES : oidx;
            my_off = off[c];
        }
    }

    for (int j = 0; j < 16; ++j) {
        const int r = wv * 16 + j;
        int base = __builtin_amdgcn_readfirstlane(__shfl(my_off, j));
        int end  = __builtin_amdgcn_readfirstlane(__shfl(my_off, j + 1));

        f32x4 a0 = f32x4{0.f,0.f,0.f,0.f}, a1 = a0, a2 = a0, a3 = a0;
        int i = base;
        // 8 edges per trip: 4 pair loads + 16 feature loads, all independent
        for (; i + 8 <= end; i += 8) {
            i32x2 p0 = *(const i32x2*)(pairs + 2 * (size_t)(i + 0 + eh));
            i32x2 p1 = *(const i32x2*)(pairs + 2 * (size_t)(i + 2 + eh));
            i32x2 p2 = *(const i32x2*)(pairs + 2 * (size_t)(i + 4 + eh));
            i32x2 p3 = *(const i32x2*)(pairs + 2 * (size_t)(i + 6 + eh));
            f32x4 e0 = *(const f32x4*)(edge_feat + (size_t)p0.x * D_IN + ln * 4);
            f32x4 g0 = *(const f32x4*)(feat      + (size_t)p0.y * D_IN + ln * 4);
            f32x4 e1 = *(const f32x4*)(edge_feat + (size_t)p1.x * D_IN + ln * 4);
            f32x4 g1 = *(const f32x4*)(feat      + (size_t)p1.y * D_IN + ln * 4);
            f32x4 e2 = *(const f32x4*)(edge_feat + (size_t)p2.x * D_IN + ln * 4);
            f32x4 g2 = *(const f32x4*)(feat      + (size_t)p2.y * D_IN + ln * 4);
            f32x4 e3 = *(const f32x4*)(edge_feat + (size_t)p3.x * D_IN + ln * 4);
            f32x4 g3 = *(const f32x4*)(feat      + (size_t)p3.y * D_IN + ln * 4);
            a0 += e0 + g0;
            a1 += e1 + g1;
            a2 += e2 + g2;
            a3 += e3 + g3;
        }
        // 4 edges per trip
        for (; i + 4 <= end; i += 4) {
            i32x2 p0 = *(const i32x2*)(pairs + 2 * (size_t)(i + 0 + eh));
            i32x2 p1 = *(const i32x2*)(pairs + 2 * (size_t)(i + 2 + eh));
            f32x4 e0 = *(const f32x4*)(edge_feat + (size_t)p0.x * D_IN + ln * 4);
            f32x4 g0 = *(const f32x4*)(feat      + (size_t)p0.y * D_IN + ln * 4);
            f32x4 e1 = *(const f32x4*)(edge_feat + (size_t)p1.x * D_IN + ln * 4);
            f32x4 g1 = *(const f32x4*)(feat      + (size_t)p1.y * D_IN + ln * 4);
            a0 += e0 + g0;
            a1 += e1 + g1;
        }
        // 2 edges per trip (half-wave predicated on the last odd edge)
        for (; i < end; i += 2) {
            if (i + eh < end) {
                i32x2 p = *(const i32x2*)(pairs + 2 * (size_t)(i + eh));
                f32x4 e = *(const f32x4*)(edge_feat + (size_t)p.x * D_IN + ln * 4);
                f32x4 g = *(const f32x4*)(feat      + (size_t)p.y * D_IN + ln * 4);
                a0 += e + g;
            }
        }
        f32x4 s = (a0 + a1) + (a2 + a3);
        // combine half-waves (lane L + lane L^32 hold same columns)
        s[0] += __shfl_xor(s[0], 32);
        s[1] += __shfl_xor(s[1], 32);
        s[2] += __shfl_xor(s[2], 32);
        s[3] += __shfl_xor(s[3], 32);
        if (eh == 0) {
            s16x4 hv;
            __hip_bfloat16 b0 = __float2bfloat16(s[0]); hv[0] = *(short*)&b0;
            __hip_bfloat16 c1 = __float2bfloat16(s[1]); hv[1] = *(short*)&c1;
            __hip_bfloat16 c2 = __float2bfloat16(s[2]); hv[2] = *(short*)&c2;
            __hip_bfloat16 c3 = __float2bfloat16(s[3]); hv[3] = *(short*)&c3;
            *(s16x4*)&h_s[r * HS_STRIDE + ln * 4] = hv;
        }
    }
    __syncthreads();

    // ---- A fragments for layer 1 (held in registers for all chunks) ----
    bf16x8 afrag[4][4];
    #pragma unroll
    for (int mt = 0; mt < 4; ++mt)
        #pragma unroll
        for (int ks = 0; ks < 4; ++ks)
            afrag[mt][ks] = *(const bf16x8*)&h_s[(mt * 16 + lid) * HS_STRIDE + ks * 32 + half * 8];

    f32x4 acc[4][2];
    #pragma unroll
    for (int mt = 0; mt < 4; ++mt) {
        acc[mt][0] = f32x4{0.f, 0.f, 0.f, 0.f};
        acc[mt][1] = f32x4{0.f, 0.f, 0.f, 0.f};
    }

    const int ncol1 = wv * 16 + lid;   // within-chunk hidden column for layer-1 B

    int pb = 0;
    for (int jb = 0; jb < D_HID; jb += 64, pb ^= 1) {
        // ---- layer 1 ----
        float bias = b1[jb + ncol1];
        bf16x8 bfrag[4];
        #pragma unroll
        for (int ks = 0; ks < 4; ++ks)
            bfrag[ks] = *(const bf16x8*)&w1s[(size_t)(jb + ncol1) * 128 + ks * 32 + half * 8];

        f32x4 c1[4];
        #pragma unroll
        for (int mt = 0; mt < 4; ++mt) {
            f32x4 c = f32x4{bias, bias, bias, bias};
            #pragma unroll
            for (int ks = 0; ks < 4; ++ks)
                c = __builtin_amdgcn_mfma_f32_16x16x32_bf16(afrag[mt][ks], bfrag[ks], c, 0, 0, 0);
            c1[mt] = c;
        }

        // write this chunk into q_s[pb]; previous chunk's reads of q_s[pb^1]
        // are separated from the NEXT write to pb^1 by this barrier.
        #pragma unroll
        for (int mt = 0; mt < 4; ++mt) {
            #pragma unroll
            for (int r = 0; r < 4; ++r) {
                float v = fmaxf(c1[mt][r], 0.f);
                __hip_bfloat16 bv = __float2bfloat16(v);
                q_s[pb][(mt * 16 + half * 4 + r) * QS_STRIDE + wv * 16 + lid] = *(short*)&bv;
            }
        }
        __syncthreads();

        // ---- layer 2 ----
        bf16x8 a2f[4][2];
        #pragma unroll
        for (int mt = 0; mt < 4; ++mt)
            #pragma unroll
            for (int ks = 0; ks < 2; ++ks)
                a2f[mt][ks] = *(const bf16x8*)&q_s[pb][(mt * 16 + lid) * QS_STRIDE + ks * 32 + half * 8];

        #pragma unroll
        for (int nt = 0; nt < 2; ++nt) {
            #pragma unroll
            for (int ks = 0; ks < 2; ++ks) {
                bf16x8 b2f = *(const bf16x8*)&w2s[(size_t)(wv * 32 + nt * 16 + lid) * 1024 + jb + ks * 32 + half * 8];
                #pragma unroll
                for (int mt = 0; mt < 4; ++mt)
                    acc[mt][nt] = __builtin_amdgcn_mfma_f32_16x16x32_bf16(a2f[mt][ks], b2f, acc[mt][nt], 0, 0, 0);
            }
        }
    }

    // ---- epilogue ----
    #pragma unroll
    for (int nt = 0; nt < 2; ++nt) {
        int col = wv * 32 + nt * 16 + lid;
        float bv = b2[col];
        #pragma unroll
        for (int mt = 0; mt < 4; ++mt) {
            #pragma unroll
            for (int r = 0; r < 4; ++r) {
                int row = nb + mt * 16 + half * 4 + r;
                if (row < N_NODES)
                    out[(size_t)row * D_OUT + col] = acc[mt][nt][r] + bv;
            }
        }
    }
}

// ---------------------------------------------------------------------------
extern "C" void kernel_launch(void* const* d_in, const int* in_sizes, int n_in,
                              void* d_out, int out_size, void* d_ws, size_t ws_size,
                              hipStream_t stream) {
    const float* feat      = (const float*)d_in[0];
    const float* edge_feat = (const float*)d_in[1];
    const int*   src       = (const int*)d_in[2];
    const int*   dst       = (const int*)d_in[3];
    const float* W1        = (const float*)d_in[4];
    const float* b1        = (const float*)d_in[5];
    const float* W2        = (const float*)d_in[6];
    const float* b2        = (const float*)d_in[7];
    float* out = (float*)d_out;

    char* ws = (char*)d_ws;
    int*   pairs  = (int*)(ws + WS_PAIRS);
    int*   off    = (int*)(ws + WS_OFF);
    int*   cursor = (int*)(ws + WS_CURSOR);
    int*   deg    = (int*)(ws + WS_DEG);
    int*   bsum   = (int*)(ws + WS_BSUM);
    __hip_bfloat16* w1t = (__hip_bfloat16*)(ws + WS_W1T);
    __hip_bfloat16* w2t = (__hip_bfloat16*)(ws + WS_W2T);

    hipMemsetAsync(deg, 0, (size_t)N_NODES * sizeof(int), stream);

    // CSR build
    hist_kernel<<<(N_EDGES + 255) / 256, 256, 0, stream>>>(dst, deg);
    scan1_kernel<<<SCAN_NB, 256, 0, stream>>>(deg, bsum);
    scan2_kernel<<<1, 256, 0, stream>>>(bsum, off);
    scan3_kernel<<<SCAN_NB, 256, 0, stream>>>(deg, bsum, off, cursor);
    fill_kernel<<<(N_EDGES + 255) / 256, 256, 0, stream>>>(dst, src, cursor, pairs);

    // both weight transposes in one launch
    transpose_cvt2_kernel<<<256, 256, 0, stream>>>(W1, w1t, W2, w2t);

    // fused gather + MFMA MLP
    fused_gnn_kernel<<<(N_NODES + 63) / 64, 256, 0, stream>>>(
        feat, edge_feat, pairs, off, w1t, b1, w2t, b2, out);
}